// Round 15
// baseline (228.487 us; speedup 1.0000x reference)
//
#include <hip/hip_runtime.h>

// Problem constants (fixed by setup_inputs): B=8, H=W=512, D=32, K=64
#define B_    8
#define N_    (512 * 512)
#define D_    32
#define K_    64
#define TPB   256
#define NWAVE (TPB / 64)
#define KROW  36                 // row stride (floats): 16B-aligned, rotates banks
#define TABW  (K_ * KROW)        // 2304 floats per wave-private table
#define REC   (K_ * D_ + K_)     // per-block partial record: 2048 sums + 64 counts
#define RECQ  (REC / 4)          // 528 float4 quads per record
#define NGRP  (B_ * 8)           // 64 L1 reduce groups (8 per batch)

// ---------------------------------------------------------------------------
// ONE kernel: stage1 (r9-proven, untouched) + fused reduction/loss tail via
// the last-block-done pattern. Producers: write partials -> __threadfence()
// -> atomicAdd(L1 counter). The 16th block of a group reduces it (overlapping
// stage1 stragglers on other CUs); the 8th group of a batch computes that
// batch's pair loss (LDS scratch reuses s_tab); the 8th batch writes out[0].
// All computed values are completion-order-independent -> deterministic.
// Counters are zeroed by a hipMemsetAsync before the kernel (graph-safe).
// ---------------------------------------------------------------------------
#define PROC(L0,L1,L2,L3,L4,L5,L6,L7, V, PBASE)                               \
  {                                                                           \
    int lb = egl < 4 ? (egl < 2 ? (egl == 0 ? L0 : L1)                        \
                                : (egl == 2 ? L2 : L3))                       \
                     : (egl < 6 ? (egl == 4 ? L4 : L5)                        \
                                : (egl == 6 ? L6 : L7));                      \
    const int m0 = (lb == L0), m1 = (lb == L1), m2 = (lb == L2),              \
              m3 = (lb == L3), m4 = (lb == L4), m5 = (lb == L5),              \
              m6 = (lb == L6), m7 = (lb == L7);                               \
    const int order = (g0 & m0) + (g1 & m1) + (g2 & m2) + (g3 & m3) +         \
                      (g4 & m4) + (g5 & m5) + (g6 & m6);                      \
    const int nsame = m0 + m1 + m2 + m3 + m4 + m5 + m6 + m7;                  \
    const float4 vc = V;                                                      \
    const int pb = (PBASE);                                                   \
    if (pb < N_) {        /* uniform branch */                                \
      const int* lp = lab + bbase + pb + wb;   /* wave-uniform -> s_load */   \
      L0 = lp[0]; L1 = lp[1]; L2 = lp[2]; L3 = lp[3];                         \
      L4 = lp[4]; L5 = lp[5]; L6 = lp[6]; L7 = lp[7];                         \
      V = embv[(bbase + pb + eg) * 8 + d4];                                   \
    }                                                                         \
    const int a = lb * KROW + d4 * 4;                                         \
    if (order == 0) {                                                         \
      float4 cur = *reinterpret_cast<const float4*>(tab + a);                 \
      cur.x += vc.x; cur.y += vc.y; cur.z += vc.z; cur.w += vc.w;             \
      *reinterpret_cast<float4*>(tab + a) = cur;                              \
      if (d4 == 0) cnt[lb] += (float)nsame;                                   \
    } else {  /* rare; lands after the write in issue order */                \
      atomicAdd(&tab[a + 0], vc.x);                                           \
      atomicAdd(&tab[a + 1], vc.y);                                           \
      atomicAdd(&tab[a + 2], vc.z);                                           \
      atomicAdd(&tab[a + 3], vc.w);                                           \
    }                                                                         \
  }

__global__ __launch_bounds__(TPB) void mono_kernel(
    const float* __restrict__ emb, const int* __restrict__ lab,
    float* __restrict__ partials, float* __restrict__ part2,
    float* __restrict__ batch_loss, int* __restrict__ counters,
    float* __restrict__ out, int blk_per_b)
{
    __shared__ __align__(16) float s_tab[NWAVE * TABW];
    __shared__ float s_cnt[NWAVE * K_];
    __shared__ int   s_role;

    for (int i = threadIdx.x; i < NWAVE * TABW; i += TPB) s_tab[i] = 0.f;
    for (int i = threadIdx.x; i < NWAVE * K_;  i += TPB) s_cnt[i] = 0.f;
    __syncthreads();

    const int tid  = threadIdx.x;
    const int wave = tid >> 6;
    const int lane = tid & 63;
    const int egl  = lane >> 3;          // element slot within wave: 0..7
    const int d4   = lane & 7;           // float4 slice within element: 0..7
    const int eg   = wave * 8 + egl;     // element slot within block-iter

    const int g0 = (0 < egl), g1 = (1 < egl), g2 = (2 < egl), g3 = (3 < egl),
              g4 = (4 < egl), g5 = (5 < egl), g6 = (6 < egl);

    float* __restrict__ tab = s_tab + wave * TABW;
    float* __restrict__ cnt = s_cnt + wave * K_;

    const int blk = blockIdx.x;
    const int b   = blk / blk_per_b;
    const int bib = blk - b * blk_per_b;
    const long long bbase = (long long)b * N_;
    const float4* __restrict__ embv = reinterpret_cast<const float4*>(emb);
    const int STEP = blk_per_b * 32;
    const int wb = __builtin_amdgcn_readfirstlane(wave * 8);

    int ib = bib * 32;

    // prologue: fill both pipeline stages (A @ ib, B @ ib+STEP)
    int a0, a1, a2, a3, a4, a5, a6, a7;
    float4 va;
    {
        const int* lp = lab + bbase + ib + wb;
        a0 = lp[0]; a1 = lp[1]; a2 = lp[2]; a3 = lp[3];
        a4 = lp[4]; a5 = lp[5]; a6 = lp[6]; a7 = lp[7];
        va = embv[(bbase + ib + eg) * 8 + d4];
    }
    int b0 = 0, b1 = 0, b2 = 0, b3 = 0, b4 = 0, b5 = 0, b6 = 0, b7 = 0;
    float4 vb = make_float4(0.f, 0.f, 0.f, 0.f);
    if (ib + STEP < N_) {
        const int* lp = lab + bbase + ib + STEP + wb;
        b0 = lp[0]; b1 = lp[1]; b2 = lp[2]; b3 = lp[3];
        b4 = lp[4]; b5 = lp[5]; b6 = lp[6]; b7 = lp[7];
        vb = embv[(bbase + ib + STEP + eg) * 8 + d4];
    }

    for (;;) {
        PROC(a0, a1, a2, a3, a4, a5, a6, a7, va, ib + 2 * STEP);
        ib += STEP;
        if (ib >= N_) break;
        PROC(b0, b1, b2, b3, b4, b5, b6, b7, vb, ib + 2 * STEP);
        ib += STEP;
        if (ib >= N_) break;
    }
    __syncthreads();

    // merge the 4 wave tables, write one partial record per block
    float* outp = partials + (size_t)blk * REC;
    for (int i = tid; i < K_ * D_; i += TPB) {
        int k = i >> 5, d = i & 31;
        float s = 0.f;
#pragma unroll
        for (int w = 0; w < NWAVE; ++w) s += s_tab[w * TABW + k * KROW + d];
        outp[i] = s;
    }
    if (tid < K_) {
        float c = 0.f;
#pragma unroll
        for (int w = 0; w < NWAVE; ++w) c += s_cnt[w * K_ + tid];
        outp[K_ * D_ + tid] = c;
    }

    // ===== fused tail: last-block-done chaining ==============================
    const int gsize = blk_per_b >> 3;        // producer blocks per L1 group
    const int g     = blk / gsize;           // L1 group id: 0..NGRP-1

    __syncthreads();                          // all partial stores issued+waited
    if (tid == 0) {
        __threadfence();                      // release partials
        s_role = (atomicAdd(&counters[g], 1) == gsize - 1);
    }
    __syncthreads();
    if (!s_role) return;
    __threadfence();                          // acquire group's partials

    // ---- L1 reduce (was stage2a): sum gsize records -> part2[g] ----------
    {
        const float4* __restrict__ p4 = reinterpret_cast<const float4*>(partials)
            + (size_t)(g * gsize) * RECQ;
        float4* __restrict__ o4 = reinterpret_cast<float4*>(part2)
            + (size_t)g * RECQ;
        float4 acc0 = make_float4(0.f, 0.f, 0.f, 0.f);
        float4 acc1 = acc0, acc2 = acc0;
#pragma unroll 4
        for (int r = 0; r < gsize; ++r) {
            const float4* rp = p4 + (size_t)r * RECQ;
            float4 v0 = rp[tid];
            float4 v1 = rp[tid + 256];
            acc0.x += v0.x; acc0.y += v0.y; acc0.z += v0.z; acc0.w += v0.w;
            acc1.x += v1.x; acc1.y += v1.y; acc1.z += v1.z; acc1.w += v1.w;
            if (tid < 16) {
                float4 v2 = rp[tid + 512];
                acc2.x += v2.x; acc2.y += v2.y; acc2.z += v2.z; acc2.w += v2.w;
            }
        }
        o4[tid]       = acc0;
        o4[tid + 256] = acc1;
        if (tid < 16) o4[tid + 512] = acc2;
    }
    __syncthreads();                          // part2 stores issued+waited
    if (tid == 0) {
        __threadfence();                      // release part2[g]
        s_role = (atomicAdd(&counters[NGRP + b], 1) == 7);
    }
    __syncthreads();
    if (!s_role) return;
    __threadfence();                          // acquire batch's part2

    // ---- L2: batch pair loss (was loss8); LDS scratch carved from s_tab --
    {
        float4* s_cent4 = reinterpret_cast<float4*>(s_tab);   // 512 quads
        float*  s_cntsh = s_tab + 2048;
        float*  s_pres  = s_tab + 2112;
        float*  s_wred  = s_tab + 2176;

        const float4* __restrict__ p4 = reinterpret_cast<const float4*>(part2)
            + (size_t)(b * 8) * RECQ;

        float4 acc0 = make_float4(0.f, 0.f, 0.f, 0.f);
        float4 acc1 = acc0, acc2 = acc0;
#pragma unroll 8
        for (int c = 0; c < 8; ++c) {
            const float4* rp = p4 + (size_t)c * RECQ;
            float4 v0 = rp[tid];
            float4 v1 = rp[tid + 256];
            acc0.x += v0.x; acc0.y += v0.y; acc0.z += v0.z; acc0.w += v0.w;
            acc1.x += v1.x; acc1.y += v1.y; acc1.z += v1.z; acc1.w += v1.w;
            if (tid < 16) {
                float4 v2 = rp[tid + 512];
                acc2.x += v2.x; acc2.y += v2.y; acc2.z += v2.z; acc2.w += v2.w;
            }
        }
        __syncthreads();   // s_tab is dead (stage1 done); safe to overwrite

        // scatter: quad q (<512) -> s_cent4[(q&7)*64 + (q>>3)]
        s_cent4[(tid & 7) * K_ + (tid >> 3)] = acc0;
        {
            const int q1 = tid + 256;
            s_cent4[(q1 & 7) * K_ + (q1 >> 3)] = acc1;
        }
        if (tid < 16) reinterpret_cast<float4*>(s_cntsh)[tid] = acc2;
        __syncthreads();

        if (tid < K_) s_pres[tid] = (s_cntsh[tid] > 0.5f) ? 1.f : 0.f;
        for (int i = tid; i < 8 * K_; i += TPB) {
            float inv = 1.0f / fmaxf(s_cntsh[i & 63], 1.0f);
            float4 c = s_cent4[i];
            c.x *= inv; c.y *= inv; c.z *= inv; c.w *= inv;
            s_cent4[i] = c;
        }
        __syncthreads();

        float4 cb[8];
#pragma unroll
        for (int j = 0; j < 8; ++j) cb[j] = s_cent4[j * K_ + lane];
        const float pres2 = s_pres[lane];

        float acc = 0.f;
#pragma unroll 4
        for (int t = 0; t < 16; ++t) {
            const int k1 = wave * 16 + t;
            float dist = 0.f;
#pragma unroll
            for (int j = 0; j < 8; ++j) {
                float4 a = s_cent4[j * K_ + k1];   // wave-uniform broadcast
                dist += fabsf(a.x - cb[j].x) + fabsf(a.y - cb[j].y)
                      + fabsf(a.z - cb[j].z) + fabsf(a.w - cb[j].w);
            }
            float h = fmaxf(0.25f - dist, 0.f);
            float valid = (k1 < lane) ? s_pres[k1] * pres2 : 0.f;
            acc += valid * h * h;
        }
#pragma unroll
        for (int m = 32; m > 0; m >>= 1) acc += __shfl_xor(acc, m);
        if (lane == 0) s_wred[wave] = acc;
        __syncthreads();
        if (tid == 0) {
            float s = s_wred[0] + s_wred[1] + s_wred[2] + s_wred[3];
            float n = 0.f;
            for (int k = 0; k < K_; ++k) n += s_pres[k];
            float ncomp = n * (n - 1.f) * 0.5f;
            batch_loss[b] = (ncomp > 0.f) ? (s / ncomp) : 0.f;
            __threadfence();                  // release batch_loss[b]
            s_role = (atomicAdd(&counters[NGRP + B_], 1) == B_ - 1);
        }
    }
    __syncthreads();
    if (!s_role) return;

    // ---- L3: final average -----------------------------------------------
    if (tid == 0) {
        __threadfence();                      // acquire all batch losses
        float t = 0.f;
#pragma unroll
        for (int bb = 0; bb < B_; ++bb) t += batch_loss[bb];
        out[0] = t * (1.0f / (float)B_);
    }
}

// ---------------------------------------------------------------------------
extern "C" void kernel_launch(void* const* d_in, const int* in_sizes, int n_in,
                              void* d_out, int out_size, void* d_ws, size_t ws_size,
                              hipStream_t stream)
{
    const float* emb = (const float*)d_in[0];
    const int*   lab = (const int*)d_in[1];
    float*       out = (float*)d_out;
    float*       ws  = (float*)d_ws;

    int blk_per_b = 128;
    while (blk_per_b > 8) {
        size_t need = ((size_t)(blk_per_b * B_) * REC          // partials
                       + (size_t)NGRP * REC                    // part2
                       + B_) * sizeof(float)
                      + (NGRP + B_ + 1) * sizeof(int);         // counters
        if (need <= ws_size) break;
        blk_per_b >>= 1;
    }
    const int nblk = blk_per_b * B_;

    float* partials   = ws;
    float* part2      = ws + (size_t)nblk * REC;
    float* batch_loss = part2 + (size_t)NGRP * REC;
    int*   counters   = (int*)(batch_loss + B_);

    // zero the chaining counters (tiny stream memset; graph-capturable)
    hipMemsetAsync(counters, 0, (NGRP + B_ + 1) * sizeof(int), stream);

    mono_kernel<<<nblk, TPB, 0, stream>>>(emb, lab, partials, part2,
                                          batch_loss, counters, out, blk_per_b);
}

// Round 16
// 85.810 us; speedup vs baseline: 2.6627x; 2.6627x over previous
//
#include <hip/hip_runtime.h>

// Problem constants (fixed by setup_inputs): B=8, H=W=512, D=32, K=64
#define B_    8
#define N_    (512 * 512)
#define D_    32
#define K_    64
#define TPB   256
#define NWAVE (TPB / 64)
#define KROW  36                 // row stride (floats): 16B-aligned, rotates banks
#define TABW  (K_ * KROW)        // 2304 floats per wave-private table
#define REC   (K_ * D_ + K_)     // per-block partial record: 2048 sums + 64 counts
#define RECQ  (REC / 4)          // 528 float4 quads per record
#define NGRP  (B_ * 8)           // 64 L1 reduce groups (8 per batch)

// ---------------------------------------------------------------------------
// Stage 1: per-block partial segment sums — r9 VERBATIM (best measured:
// 74.7 us total). No fences here: stream ordering makes partials visible to
// the tail kernel (r15 lesson: device fences in the 1024-block kernel
// thrash L2 and cost 3x).
// ---------------------------------------------------------------------------
#define PROC(L0,L1,L2,L3,L4,L5,L6,L7, V, PBASE)                               \
  {                                                                           \
    int lb = egl < 4 ? (egl < 2 ? (egl == 0 ? L0 : L1)                        \
                                : (egl == 2 ? L2 : L3))                       \
                     : (egl < 6 ? (egl == 4 ? L4 : L5)                        \
                                : (egl == 6 ? L6 : L7));                      \
    const int m0 = (lb == L0), m1 = (lb == L1), m2 = (lb == L2),              \
              m3 = (lb == L3), m4 = (lb == L4), m5 = (lb == L5),              \
              m6 = (lb == L6), m7 = (lb == L7);                               \
    const int order = (g0 & m0) + (g1 & m1) + (g2 & m2) + (g3 & m3) +         \
                      (g4 & m4) + (g5 & m5) + (g6 & m6);                      \
    const int nsame = m0 + m1 + m2 + m3 + m4 + m5 + m6 + m7;                  \
    const float4 vc = V;                                                      \
    const int pb = (PBASE);                                                   \
    if (pb < N_) {        /* uniform branch */                                \
      const int* lp = lab + bbase + pb + wb;   /* wave-uniform -> s_load */   \
      L0 = lp[0]; L1 = lp[1]; L2 = lp[2]; L3 = lp[3];                         \
      L4 = lp[4]; L5 = lp[5]; L6 = lp[6]; L7 = lp[7];                         \
      V = embv[(bbase + pb + eg) * 8 + d4];                                   \
    }                                                                         \
    const int a = lb * KROW + d4 * 4;                                         \
    if (order == 0) {                                                         \
      float4 cur = *reinterpret_cast<const float4*>(tab + a);                 \
      cur.x += vc.x; cur.y += vc.y; cur.z += vc.z; cur.w += vc.w;             \
      *reinterpret_cast<float4*>(tab + a) = cur;                              \
      if (d4 == 0) cnt[lb] += (float)nsame;                                   \
    } else {  /* rare; lands after the write in issue order */                \
      atomicAdd(&tab[a + 0], vc.x);                                           \
      atomicAdd(&tab[a + 1], vc.y);                                           \
      atomicAdd(&tab[a + 2], vc.z);                                           \
      atomicAdd(&tab[a + 3], vc.w);                                           \
    }                                                                         \
  }

__global__ __launch_bounds__(TPB) void seg_partial_kernel(
    const float* __restrict__ emb, const int* __restrict__ lab,
    float* __restrict__ partials, int blk_per_b)
{
    __shared__ __align__(16) float s_tab[NWAVE * TABW];
    __shared__ float s_cnt[NWAVE * K_];

    for (int i = threadIdx.x; i < NWAVE * TABW; i += TPB) s_tab[i] = 0.f;
    for (int i = threadIdx.x; i < NWAVE * K_;  i += TPB) s_cnt[i] = 0.f;
    __syncthreads();

    const int tid  = threadIdx.x;
    const int wave = tid >> 6;
    const int lane = tid & 63;
    const int egl  = lane >> 3;          // element slot within wave: 0..7
    const int d4   = lane & 7;           // float4 slice within element: 0..7
    const int eg   = wave * 8 + egl;     // element slot within block-iter

    const int g0 = (0 < egl), g1 = (1 < egl), g2 = (2 < egl), g3 = (3 < egl),
              g4 = (4 < egl), g5 = (5 < egl), g6 = (6 < egl);

    float* __restrict__ tab = s_tab + wave * TABW;
    float* __restrict__ cnt = s_cnt + wave * K_;

    const int blk = blockIdx.x;
    const int b   = blk / blk_per_b;
    const int bib = blk - b * blk_per_b;
    const long long bbase = (long long)b * N_;
    const float4* __restrict__ embv = reinterpret_cast<const float4*>(emb);
    const int STEP = blk_per_b * 32;
    const int wb = __builtin_amdgcn_readfirstlane(wave * 8);

    int ib = bib * 32;

    int a0, a1, a2, a3, a4, a5, a6, a7;
    float4 va;
    {
        const int* lp = lab + bbase + ib + wb;
        a0 = lp[0]; a1 = lp[1]; a2 = lp[2]; a3 = lp[3];
        a4 = lp[4]; a5 = lp[5]; a6 = lp[6]; a7 = lp[7];
        va = embv[(bbase + ib + eg) * 8 + d4];
    }
    int b0 = 0, b1 = 0, b2 = 0, b3 = 0, b4 = 0, b5 = 0, b6 = 0, b7 = 0;
    float4 vb = make_float4(0.f, 0.f, 0.f, 0.f);
    if (ib + STEP < N_) {
        const int* lp = lab + bbase + ib + STEP + wb;
        b0 = lp[0]; b1 = lp[1]; b2 = lp[2]; b3 = lp[3];
        b4 = lp[4]; b5 = lp[5]; b6 = lp[6]; b7 = lp[7];
        vb = embv[(bbase + ib + STEP + eg) * 8 + d4];
    }

    for (;;) {
        PROC(a0, a1, a2, a3, a4, a5, a6, a7, va, ib + 2 * STEP);
        ib += STEP;
        if (ib >= N_) break;
        PROC(b0, b1, b2, b3, b4, b5, b6, b7, vb, ib + 2 * STEP);
        ib += STEP;
        if (ib >= N_) break;
    }
    __syncthreads();

    float* out = partials + (size_t)blk * REC;
    for (int i = tid; i < K_ * D_; i += TPB) {
        int k = i >> 5, d = i & 31;
        float s = 0.f;
#pragma unroll
        for (int w = 0; w < NWAVE; ++w) s += s_tab[w * TABW + k * KROW + d];
        out[i] = s;
    }
    if (tid < K_) {
        float c = 0.f;
#pragma unroll
        for (int w = 0; w < NWAVE; ++w) c += s_cnt[w * K_ + tid];
        out[K_ * D_ + tid] = c;
    }
}

// ---------------------------------------------------------------------------
// Fused tail: ONE kernel, 64 blocks (group g = blockIdx.x; batch b = g>>3).
// Each block: (a) L1-reduce its 16 records -> part2[g] (r9 stage2a body);
// (b) last-done of a batch's 8 groups computes the pair loss (r9 loss8 body);
// (c) last-done batch writes out[0]. Fences: only ~72 total among 64 small
// blocks (r15's 1024-producer fences were the disaster; this is cheap).
// Deterministic: all values are completion-order-independent.
// ---------------------------------------------------------------------------
__global__ __launch_bounds__(TPB) void tail_kernel(
    const float* __restrict__ partials, float* __restrict__ part2,
    float* __restrict__ batch_loss, int* __restrict__ counters,
    float* __restrict__ out, int rpc)
{
    __shared__ __align__(16) float4 s_cent4[8 * K_];  // [j][k]
    __shared__ float s_cntsh[K_];
    __shared__ float s_pres[K_];
    __shared__ float s_wred[NWAVE];
    __shared__ int   s_role;

    const int g   = blockIdx.x;          // 0..NGRP-1
    const int b   = g >> 3;
    const int tid = threadIdx.x;

    // ---- (a) L1 reduce: rpc records -> part2[g] --------------------------
    {
        const float4* __restrict__ p4 = reinterpret_cast<const float4*>(partials)
            + (size_t)(g * rpc) * RECQ;
        float4* __restrict__ o4 = reinterpret_cast<float4*>(part2)
            + (size_t)g * RECQ;
        float4 acc0 = make_float4(0.f, 0.f, 0.f, 0.f);
        float4 acc1 = acc0, acc2 = acc0;
#pragma unroll 4
        for (int r = 0; r < rpc; ++r) {
            const float4* rp = p4 + (size_t)r * RECQ;
            float4 v0 = rp[tid];
            float4 v1 = rp[tid + 256];
            acc0.x += v0.x; acc0.y += v0.y; acc0.z += v0.z; acc0.w += v0.w;
            acc1.x += v1.x; acc1.y += v1.y; acc1.z += v1.z; acc1.w += v1.w;
            if (tid < 16) {
                float4 v2 = rp[tid + 512];
                acc2.x += v2.x; acc2.y += v2.y; acc2.z += v2.z; acc2.w += v2.w;
            }
        }
        o4[tid]       = acc0;
        o4[tid + 256] = acc1;
        if (tid < 16) o4[tid + 512] = acc2;
    }
    __syncthreads();                          // part2 stores issued+waited
    if (tid == 0) {
        __threadfence();                      // release part2[g]
        s_role = (atomicAdd(&counters[b], 1) == 7);
    }
    __syncthreads();
    if (!s_role) return;
    __threadfence();                          // acquire batch's part2

    // ---- (b) batch pair loss (r9 loss8 body) -----------------------------
    const float4* __restrict__ p4 = reinterpret_cast<const float4*>(part2)
        + (size_t)(b * 8) * RECQ;

    float4 acc0 = make_float4(0.f, 0.f, 0.f, 0.f);
    float4 acc1 = acc0, acc2 = acc0;
#pragma unroll 8
    for (int c = 0; c < 8; ++c) {
        const float4* rp = p4 + (size_t)c * RECQ;
        float4 v0 = rp[tid];
        float4 v1 = rp[tid + 256];
        acc0.x += v0.x; acc0.y += v0.y; acc0.z += v0.z; acc0.w += v0.w;
        acc1.x += v1.x; acc1.y += v1.y; acc1.z += v1.z; acc1.w += v1.w;
        if (tid < 16) {
            float4 v2 = rp[tid + 512];
            acc2.x += v2.x; acc2.y += v2.y; acc2.z += v2.z; acc2.w += v2.w;
        }
    }

    // scatter: quad q (<512) -> s_cent4[(q&7)*64 + (q>>3)]
    s_cent4[(tid & 7) * K_ + (tid >> 3)] = acc0;
    {
        const int q1 = tid + 256;
        s_cent4[(q1 & 7) * K_ + (q1 >> 3)] = acc1;
    }
    if (tid < 16) reinterpret_cast<float4*>(s_cntsh)[tid] = acc2;
    __syncthreads();

    if (tid < K_) s_pres[tid] = (s_cntsh[tid] > 0.5f) ? 1.f : 0.f;
    for (int i = tid; i < 8 * K_; i += TPB) {
        float inv = 1.0f / fmaxf(s_cntsh[i & 63], 1.0f);
        float4 c = s_cent4[i];
        c.x *= inv; c.y *= inv; c.z *= inv; c.w *= inv;
        s_cent4[i] = c;
    }
    __syncthreads();

    const int wave = tid >> 6, lane = tid & 63;

    float4 cb[8];
#pragma unroll
    for (int j = 0; j < 8; ++j) cb[j] = s_cent4[j * K_ + lane];
    const float pres2 = s_pres[lane];

    float acc = 0.f;
#pragma unroll 4
    for (int t = 0; t < 16; ++t) {
        const int k1 = wave * 16 + t;
        float dist = 0.f;
#pragma unroll
        for (int j = 0; j < 8; ++j) {
            float4 a = s_cent4[j * K_ + k1];   // wave-uniform broadcast
            dist += fabsf(a.x - cb[j].x) + fabsf(a.y - cb[j].y)
                  + fabsf(a.z - cb[j].z) + fabsf(a.w - cb[j].w);
        }
        float h = fmaxf(0.25f - dist, 0.f);
        float valid = (k1 < lane) ? s_pres[k1] * pres2 : 0.f;
        acc += valid * h * h;
    }
#pragma unroll
    for (int m = 32; m > 0; m >>= 1) acc += __shfl_xor(acc, m);
    if (lane == 0) s_wred[wave] = acc;
    __syncthreads();
    if (tid == 0) {
        float s = s_wred[0] + s_wred[1] + s_wred[2] + s_wred[3];
        float n = 0.f;
        for (int k = 0; k < K_; ++k) n += s_pres[k];
        float ncomp = n * (n - 1.f) * 0.5f;
        batch_loss[b] = (ncomp > 0.f) ? (s / ncomp) : 0.f;
        __threadfence();                      // release batch_loss[b]
        s_role = (atomicAdd(&counters[B_], 1) == B_ - 1);
    }
    __syncthreads();
    if (!s_role) return;

    // ---- (c) final average ----------------------------------------------
    if (tid == 0) {
        __threadfence();                      // acquire all batch losses
        float t = 0.f;
#pragma unroll
        for (int bb = 0; bb < B_; ++bb) t += batch_loss[bb];
        out[0] = t * (1.0f / (float)B_);
    }
}

// ---------------------------------------------------------------------------
extern "C" void kernel_launch(void* const* d_in, const int* in_sizes, int n_in,
                              void* d_out, int out_size, void* d_ws, size_t ws_size,
                              hipStream_t stream)
{
    const float* emb = (const float*)d_in[0];
    const int*   lab = (const int*)d_in[1];
    float*       out = (float*)d_out;
    float*       ws  = (float*)d_ws;

    int blk_per_b = 128;
    while (blk_per_b > 8) {
        size_t need = ((size_t)(blk_per_b * B_) * REC          // partials
                       + (size_t)NGRP * REC                    // part2
                       + B_) * sizeof(float)
                      + (B_ + 1) * sizeof(int);                // counters
        if (need <= ws_size) break;
        blk_per_b >>= 1;
    }
    const int nblk = blk_per_b * B_;
    const int rpc  = blk_per_b / 8;          // records per L1 group

    float* partials   = ws;
    float* part2      = ws + (size_t)nblk * REC;
    float* batch_loss = part2 + (size_t)NGRP * REC;
    int*   counters   = (int*)(batch_loss + B_);

    // zero the chaining counters (tiny stream memset; graph-capturable)
    hipMemsetAsync(counters, 0, (B_ + 1) * sizeof(int), stream);

    seg_partial_kernel<<<nblk, TPB, 0, stream>>>(emb, lab, partials, blk_per_b);

    tail_kernel<<<NGRP, TPB, 0, stream>>>(partials, part2, batch_loss,
                                          counters, out, rpc);
}

// Round 17
// 74.839 us; speedup vs baseline: 3.0530x; 1.1466x over previous
//
#include <hip/hip_runtime.h>

// Problem constants (fixed by setup_inputs): B=8, H=W=512, D=32, K=64
#define B_    8
#define N_    (512 * 512)
#define D_    32
#define K_    64
#define TPB   256
#define NWAVE (TPB / 64)
#define KROW  36                 // row stride (floats): 16B-aligned, rotates banks
#define TABW  (K_ * KROW)        // 2304 floats per wave-private table
#define REC   (K_ * D_ + K_)     // per-block partial record: 2048 sums + 64 counts
#define RECQ  (REC / 4)          // 528 float4 quads per record
#define NGRP  (B_ * 8)           // 64 L1 reduce groups (8 per batch)

// ---------------------------------------------------------------------------
// Stage 1: per-block partial segment sums — VALU-minimized PROC.
// Model: r9's loop issued ~55 VALU x 2cyc x 4 waves/SIMD ~= 440 cyc/group,
// balanced against ~410 cyc HBM -> both pipes saturated (explains r7/r11/r12
// nulls and r10/r13/r14 regressions). This round DELETES VALU:
//  (1) counts leave the hot loop (nsame + predicated cnt-add gone); a per-wave
//      int-histogram epilogue over the block's own labels rebuilds them.
//  (2) per-lane label load (8-lane broadcast) replaces the 11-op cndmask
//      tree; scalar s_load labels remain only for `order` (7 compares).
// ~32 VALU/iter -> issue ~256 cyc < HBM ~410 cyc -> memory-bound.
// Contiguous per-block range (r11-proven equal to strided, simpler epilogue).
// All registers NAMED (r4 scratch lesson).
// ---------------------------------------------------------------------------
#define PROC(S0,S1,S2,S3,S4,S5,S6, LBV, V, PBASE)                             \
  {                                                                           \
    const int    lbc = LBV;                                                   \
    const float4 vc  = V;                                                     \
    const int m0 = (lbc == S0), m1 = (lbc == S1), m2 = (lbc == S2),           \
              m3 = (lbc == S3), m4 = (lbc == S4), m5 = (lbc == S5),           \
              m6 = (lbc == S6);                                               \
    const int order = (g0 & m0) + (g1 & m1) + (g2 & m2) + (g3 & m3) +         \
                      (g4 & m4) + (g5 & m5) + (g6 & m6);                      \
    const int pb = (PBASE);                                                   \
    if (pb < iend) {      /* uniform branch */                                \
      const int* lp = lab + bbase + pb + wb;   /* wave-uniform -> s_load */   \
      S0 = lp[0]; S1 = lp[1]; S2 = lp[2]; S3 = lp[3];                         \
      S4 = lp[4]; S5 = lp[5]; S6 = lp[6];                                     \
      LBV = lab[bbase + pb + eg];              /* per-lane, 32B/wave */       \
      V   = embv[(bbase + pb + eg) * 8 + d4];                                 \
    }                                                                         \
    const int a = lbc * KROW + d4x4;                                          \
    if (order == 0) {                                                         \
      float4 cur = *reinterpret_cast<const float4*>(tab + a);                 \
      cur.x += vc.x; cur.y += vc.y; cur.z += vc.z; cur.w += vc.w;             \
      *reinterpret_cast<float4*>(tab + a) = cur;                              \
    } else {  /* rare (~4%); lands after the write in issue order */          \
      atomicAdd(&tab[a + 0], vc.x);                                           \
      atomicAdd(&tab[a + 1], vc.y);                                           \
      atomicAdd(&tab[a + 2], vc.z);                                           \
      atomicAdd(&tab[a + 3], vc.w);                                           \
    }                                                                         \
  }

__global__ __launch_bounds__(TPB) void seg_partial_kernel(
    const float* __restrict__ emb, const int* __restrict__ lab,
    float* __restrict__ partials, int blk_per_b)
{
    __shared__ __align__(16) float s_tab[NWAVE * TABW];
    __shared__ int s_hist[NWAVE * K_];

    for (int i = threadIdx.x; i < NWAVE * TABW; i += TPB) s_tab[i] = 0.f;
    for (int i = threadIdx.x; i < NWAVE * K_;  i += TPB) s_hist[i] = 0;
    __syncthreads();

    const int tid  = threadIdx.x;
    const int wave = tid >> 6;
    const int lane = tid & 63;
    const int egl  = lane >> 3;          // element slot within wave: 0..7
    const int d4   = lane & 7;           // float4 slice within element: 0..7
    const int eg   = wave * 8 + egl;     // element slot within block-iter
    const int d4x4 = d4 * 4;             // loop-invariant

    const int g0 = (0 < egl), g1 = (1 < egl), g2 = (2 < egl), g3 = (3 < egl),
              g4 = (4 < egl), g5 = (5 < egl), g6 = (6 < egl);

    float* __restrict__ tab = s_tab + wave * TABW;

    const int blk = blockIdx.x;
    const int b   = blk / blk_per_b;
    const int bib = blk - b * blk_per_b;
    const long long bbase = (long long)b * N_;
    const float4* __restrict__ embv = reinterpret_cast<const float4*>(emb);
    const int CHUNK = N_ / blk_per_b;    // contiguous elements per block
    const int cstart = bib * CHUNK;
    const int iend   = cstart + CHUNK;
    const int wb = __builtin_amdgcn_readfirstlane(wave * 8);

    int ib = cstart;

    // prologue: fill both pipeline stages (A @ ib, B @ ib+32)
    int a0, a1, a2, a3, a4, a5, a6, lbA;
    float4 va;
    {
        const int* lp = lab + bbase + ib + wb;
        a0 = lp[0]; a1 = lp[1]; a2 = lp[2]; a3 = lp[3];
        a4 = lp[4]; a5 = lp[5]; a6 = lp[6];
        lbA = lab[bbase + ib + eg];
        va  = embv[(bbase + ib + eg) * 8 + d4];
    }
    int b0 = 0, b1 = 0, b2 = 0, b3 = 0, b4 = 0, b5 = 0, b6 = 0, lbB = 0;
    float4 vb = make_float4(0.f, 0.f, 0.f, 0.f);
    if (ib + 32 < iend) {
        const int* lp = lab + bbase + ib + 32 + wb;
        b0 = lp[0]; b1 = lp[1]; b2 = lp[2]; b3 = lp[3];
        b4 = lp[4]; b5 = lp[5]; b6 = lp[6];
        lbB = lab[bbase + ib + 32 + eg];
        vb  = embv[(bbase + ib + 32 + eg) * 8 + d4];
    }

    for (;;) {
        PROC(a0, a1, a2, a3, a4, a5, a6, lbA, va, ib + 64);
        ib += 32;
        if (ib >= iend) break;
        PROC(b0, b1, b2, b3, b4, b5, b6, lbB, vb, ib + 64);
        ib += 32;
        if (ib >= iend) break;
    }
    __syncthreads();

    // epilogue A: per-wave int histogram of the block's own labels (counts
    // were removed from the hot loop). Each wave owns a CHUNK/4 slice.
    {
        int* whist = s_hist + wave * K_;
        const int slice = CHUNK >> 2;
        const long long sb = bbase + cstart + wave * slice;
        for (int i = lane; i < slice; i += 64)
            atomicAdd(&whist[lab[sb + i]], 1);
    }
    __syncthreads();

    // epilogue B: merge the 4 wave tables + histograms into the record
    float* out = partials + (size_t)blk * REC;
    for (int i = tid; i < K_ * D_; i += TPB) {
        int k = i >> 5, d = i & 31;
        float s = 0.f;
#pragma unroll
        for (int w = 0; w < NWAVE; ++w) s += s_tab[w * TABW + k * KROW + d];
        out[i] = s;
    }
    if (tid < K_) {
        int c = s_hist[tid] + s_hist[K_ + tid] + s_hist[2 * K_ + tid]
              + s_hist[3 * K_ + tid];
        out[K_ * D_ + tid] = (float)c;
    }
}

// ---------------------------------------------------------------------------
// Stage 2a: two-level reduction, level 1 (r9-proven).
// ---------------------------------------------------------------------------
__global__ __launch_bounds__(TPB) void seg_reduce_a(
    const float* __restrict__ partials, float* __restrict__ part2,
    int rpc, int nch)
{
    const int blk = blockIdx.x;
    const int b   = blk / nch;
    const int ch  = blk - b * nch;
    const int tid = threadIdx.x;

    const float4* __restrict__ p4 = reinterpret_cast<const float4*>(partials)
        + (size_t)((b * nch + ch) * rpc) * RECQ;
    float4* __restrict__ o4 = reinterpret_cast<float4*>(part2)
        + (size_t)blk * RECQ;

    float4 acc0 = make_float4(0.f, 0.f, 0.f, 0.f);
    float4 acc1 = acc0, acc2 = acc0;
#pragma unroll 4
    for (int r = 0; r < rpc; ++r) {
        const float4* rp = p4 + (size_t)r * RECQ;
        float4 v0 = rp[tid];
        float4 v1 = rp[tid + 256];
        acc0.x += v0.x; acc0.y += v0.y; acc0.z += v0.z; acc0.w += v0.w;
        acc1.x += v1.x; acc1.y += v1.y; acc1.z += v1.z; acc1.w += v1.w;
        if (tid < 16) {
            float4 v2 = rp[tid + 512];
            acc2.x += v2.x; acc2.y += v2.y; acc2.z += v2.z; acc2.w += v2.w;
        }
    }
    o4[tid]       = acc0;
    o4[tid + 256] = acc1;
    if (tid < 16) o4[tid + 512] = acc2;
}

// ---------------------------------------------------------------------------
// Stage 2b+3: one block per batch (r9-proven).
// ---------------------------------------------------------------------------
__global__ __launch_bounds__(TPB) void loss8_kernel(
    const float* __restrict__ part2, float* __restrict__ batch_loss,
    int nch)
{
    __shared__ __align__(16) float4 s_cent4[8 * K_];  // [j][k]
    __shared__ float s_cntsh[K_];
    __shared__ float s_pres[K_];
    __shared__ float s_wred[NWAVE];

    const int b   = blockIdx.x;
    const int tid = threadIdx.x;
    const float4* __restrict__ p4 = reinterpret_cast<const float4*>(part2)
        + (size_t)(b * nch) * RECQ;

    float4 acc0 = make_float4(0.f, 0.f, 0.f, 0.f);
    float4 acc1 = acc0, acc2 = acc0;
#pragma unroll 8
    for (int c = 0; c < nch; ++c) {
        const float4* rp = p4 + (size_t)c * RECQ;
        float4 v0 = rp[tid];
        float4 v1 = rp[tid + 256];
        acc0.x += v0.x; acc0.y += v0.y; acc0.z += v0.z; acc0.w += v0.w;
        acc1.x += v1.x; acc1.y += v1.y; acc1.z += v1.z; acc1.w += v1.w;
        if (tid < 16) {
            float4 v2 = rp[tid + 512];
            acc2.x += v2.x; acc2.y += v2.y; acc2.z += v2.z; acc2.w += v2.w;
        }
    }

    // scatter: quad q (<512) -> s_cent4[(q&7)*64 + (q>>3)]
    s_cent4[(tid & 7) * K_ + (tid >> 3)] = acc0;
    {
        const int q1 = tid + 256;
        s_cent4[(q1 & 7) * K_ + (q1 >> 3)] = acc1;
    }
    if (tid < 16) reinterpret_cast<float4*>(s_cntsh)[tid] = acc2;
    __syncthreads();

    if (tid < K_) s_pres[tid] = (s_cntsh[tid] > 0.5f) ? 1.f : 0.f;
    for (int i = tid; i < 8 * K_; i += TPB) {
        float inv = 1.0f / fmaxf(s_cntsh[i & 63], 1.0f);
        float4 c = s_cent4[i];
        c.x *= inv; c.y *= inv; c.z *= inv; c.w *= inv;
        s_cent4[i] = c;
    }
    __syncthreads();

    const int wave = tid >> 6, lane = tid & 63;

    float4 cb[8];
#pragma unroll
    for (int j = 0; j < 8; ++j) cb[j] = s_cent4[j * K_ + lane];
    const float pres2 = s_pres[lane];

    float acc = 0.f;
#pragma unroll 4
    for (int t = 0; t < 16; ++t) {
        const int k1 = wave * 16 + t;
        float dist = 0.f;
#pragma unroll
        for (int j = 0; j < 8; ++j) {
            float4 a = s_cent4[j * K_ + k1];   // wave-uniform broadcast
            dist += fabsf(a.x - cb[j].x) + fabsf(a.y - cb[j].y)
                  + fabsf(a.z - cb[j].z) + fabsf(a.w - cb[j].w);
        }
        float h = fmaxf(0.25f - dist, 0.f);
        float valid = (k1 < lane) ? s_pres[k1] * pres2 : 0.f;
        acc += valid * h * h;
    }
#pragma unroll
    for (int m = 32; m > 0; m >>= 1) acc += __shfl_xor(acc, m);
    if (lane == 0) s_wred[wave] = acc;
    __syncthreads();
    if (tid == 0) {
        float s = s_wred[0] + s_wred[1] + s_wred[2] + s_wred[3];
        float n = 0.f;
        for (int k = 0; k < K_; ++k) n += s_pres[k];
        float ncomp = n * (n - 1.f) * 0.5f;
        batch_loss[b] = (ncomp > 0.f) ? (s / ncomp) : 0.f;
    }
}

// ---------------------------------------------------------------------------
// Stage 4: average the 8 per-batch losses into out[0].
// ---------------------------------------------------------------------------
__global__ void final_kernel(const float* __restrict__ batch_loss,
                             float* __restrict__ out)
{
    if (threadIdx.x == 0) {
        float t = 0.f;
#pragma unroll
        for (int b = 0; b < B_; ++b) t += batch_loss[b];
        out[0] = t * (1.0f / (float)B_);
    }
}

// ---------------------------------------------------------------------------
extern "C" void kernel_launch(void* const* d_in, const int* in_sizes, int n_in,
                              void* d_out, int out_size, void* d_ws, size_t ws_size,
                              hipStream_t stream)
{
    const float* emb = (const float*)d_in[0];
    const int*   lab = (const int*)d_in[1];
    float*       out = (float*)d_out;
    float*       ws  = (float*)d_ws;

    int blk_per_b = 128;
    while (blk_per_b > 8) {
        size_t need = ((size_t)(blk_per_b * B_) * REC          // partials
                       + (size_t)NGRP * REC                    // part2 (max)
                       + B_) * sizeof(float);
        if (need <= ws_size) break;
        blk_per_b >>= 1;
    }
    const int nblk = blk_per_b * B_;
    const int nch  = (blk_per_b >= 8) ? 8 : blk_per_b;
    const int rpc  = blk_per_b / nch;

    float* partials   = ws;
    float* part2      = ws + (size_t)nblk * REC;
    float* batch_loss = part2 + (size_t)(B_ * nch) * REC;

    seg_partial_kernel<<<nblk, TPB, 0, stream>>>(emb, lab, partials, blk_per_b);

    seg_reduce_a<<<B_ * nch, TPB, 0, stream>>>(partials, part2, rpc, nch);

    loss8_kernel<<<B_, TPB, 0, stream>>>(part2, batch_loss, nch);

    final_kernel<<<1, 64, 0, stream>>>(batch_loss, out);
}